// Round 10
// baseline (709.170 us; speedup 1.0000x reference)
//
#include <hip/hip_runtime.h>
#include <stdint.h>
#include <math.h>

#define EMB       256
#define D_INNER   512
#define HEADDIM   64
#define NHEADS    8
#define DSTATE    128
#define DCONV     4
#define CONV_DIM  768
#define LN_EPS    1e-5f
#define NBATCH    64
#define SEQLEN    512
#define NTOK      (NBATCH*SEQLEN)   // 32768

typedef __attribute__((ext_vector_type(8))) short          short8;
typedef __attribute__((ext_vector_type(8))) unsigned short u16x8;
typedef __attribute__((ext_vector_type(4))) float          f32x4;

__device__ __forceinline__ float bfb(unsigned short u) {
    union { unsigned int i; float f; } x; x.i = ((unsigned int)u) << 16; return x.f;
}
__device__ __forceinline__ unsigned short fbf(float f) {
    union { float f; unsigned int i; } x; x.f = f;
    unsigned int i = x.i;
    unsigned int lsb = (i >> 16) & 1u;
    i += 0x7fffu + lsb;
    return (unsigned short)(i >> 16);
}

// ---------------- f32 -> bf16 convert (weights) ----------------
__global__ __launch_bounds__(256) void cvt_k(const float* __restrict__ in,
                                             unsigned short* __restrict__ out, int n) {
    int i = blockIdx.x * 256 + threadIdx.x;
    if (i < n) out[i] = fbf(in[i]);
}

// ---------------- LayerNorm (256-wide), f32 in -> bf16 out ----------------
__global__ __launch_bounds__(256) void ln_k(const float* __restrict__ in,
                                            const float* __restrict__ w,
                                            const float* __restrict__ b,
                                            unsigned short* __restrict__ out) {
    int tok = blockIdx.x, tid = threadIdx.x;
    size_t idx = (size_t)tok * 256 + tid;
    float x = in[idx];
    __shared__ float sm[8];
    float s = x;
    #pragma unroll
    for (int o = 32; o; o >>= 1) s += __shfl_down(s, o);
    if ((tid & 63) == 0) sm[tid >> 6] = s;
    __syncthreads();
    float mean = (sm[0] + sm[1] + sm[2] + sm[3]) * (1.f / 256.f);
    float d = x - mean;
    float q = d * d;
    #pragma unroll
    for (int o = 32; o; o >>= 1) q += __shfl_down(q, o);
    if ((tid & 63) == 0) sm[4 + (tid >> 6)] = q;
    __syncthreads();
    float var = (sm[4] + sm[5] + sm[6] + sm[7]) * (1.f / 256.f);
    out[idx] = fbf(d * rsqrtf(var + LN_EPS) * w[tid] + b[tid]);
}

// ---------------- weight-norm: w[o][k] = g[o]*v[o][k]/||v[o]||, f32 -> bf16 ----------------
__global__ __launch_bounds__(256) void wnorm_k(const float* __restrict__ g,
                                               const float* __restrict__ v,
                                               unsigned short* __restrict__ wout) {
    int o = blockIdx.x, tid = threadIdx.x;
    float x = v[(size_t)o * 256 + tid];
    float q = x * x;
    __shared__ float sm[4];
    #pragma unroll
    for (int d = 32; d; d >>= 1) q += __shfl_down(q, d);
    if ((tid & 63) == 0) sm[tid >> 6] = q;
    __syncthreads();
    float tot = sm[0] + sm[1] + sm[2] + sm[3];
    float scale = g[o] * rsqrtf(tot);
    wout[(size_t)o * 256 + tid] = fbf(x * scale);
}

// ---------------- MFMA GEMM: C[M,N] = A[M,K] @ B[N,K]^T, 128x128 tile ----------------
// EPI: 0 plain->bf16 | 1 in_proj split (zg | xbc) | 2 bias+res_f32 -> f32 out | 3 bias+gelu -> bf16
#define BMT 128
#define BNT 128
#define BKT 32
template<int EPI>
__global__ __launch_bounds__(256) void gemm_k(const unsigned short* __restrict__ A,
                                              const unsigned short* __restrict__ Bw,
                                              int K, int N,
                                              unsigned short* __restrict__ out_b,
                                              float* __restrict__ out_f,
                                              const float* __restrict__ bias,
                                              const float* __restrict__ res_f,
                                              unsigned short* __restrict__ out2_b) {
    __shared__ unsigned short As[BMT][BKT + 8];
    __shared__ unsigned short Bs[BNT][BKT + 8];
    int tid = threadIdx.x;
    int bm = blockIdx.x, bn = blockIdx.y;
    int lane = tid & 63, w = tid >> 6;
    int wr = w >> 1, wc = w & 1;
    int fr = lane & 15, fq = lane >> 4;
    f32x4 acc[4][4];
    #pragma unroll
    for (int m = 0; m < 4; m++)
        #pragma unroll
        for (int n = 0; n < 4; n++)
            #pragma unroll
            for (int r = 0; r < 4; r++) acc[m][n][r] = 0.f;

    int r0 = tid >> 2;           // 0..63
    int kc = (tid & 3) << 3;     // 0,8,16,24
    for (int k0 = 0; k0 < K; k0 += BKT) {
        __syncthreads();
        *(u16x8*)&As[r0][kc]      = *(const u16x8*)&A[(size_t)(bm * BMT + r0) * K + k0 + kc];
        *(u16x8*)&As[r0 + 64][kc] = *(const u16x8*)&A[(size_t)(bm * BMT + r0 + 64) * K + k0 + kc];
        *(u16x8*)&Bs[r0][kc]      = *(const u16x8*)&Bw[(size_t)(bn * BNT + r0) * K + k0 + kc];
        *(u16x8*)&Bs[r0 + 64][kc] = *(const u16x8*)&Bw[(size_t)(bn * BNT + r0 + 64) * K + k0 + kc];
        __syncthreads();
        short8 af[4], bf_[4];
        #pragma unroll
        for (int m = 0; m < 4; m++) af[m] = *(const short8*)&As[wr * 64 + m * 16 + fr][fq * 8];
        #pragma unroll
        for (int n = 0; n < 4; n++) bf_[n] = *(const short8*)&Bs[wc * 64 + n * 16 + fr][fq * 8];
        #pragma unroll
        for (int m = 0; m < 4; m++)
            #pragma unroll
            for (int n = 0; n < 4; n++)
                acc[m][n] = __builtin_amdgcn_mfma_f32_16x16x32_bf16(af[m], bf_[n], acc[m][n], 0, 0, 0);
    }

    #pragma unroll
    for (int m = 0; m < 4; m++)
        #pragma unroll
        for (int n = 0; n < 4; n++)
            #pragma unroll
            for (int r = 0; r < 4; r++) {
                int grow = bm * BMT + wr * 64 + m * 16 + fq * 4 + r;
                int gcol = bn * BNT + wc * 64 + n * 16 + fr;
                float v = acc[m][n][r];
                if (EPI == 0) {
                    out_b[(size_t)grow * N + gcol] = fbf(v);
                } else if (EPI == 1) {
                    if (gcol < 512) out_b[(size_t)grow * 512 + gcol] = fbf(v);
                    else            out2_b[(size_t)grow * 768 + (gcol - 512)] = fbf(v);
                } else if (EPI == 2) {
                    size_t idx = (size_t)grow * 256 + gcol;
                    out_f[idx] = res_f[idx] + v + bias[gcol];
                } else if (EPI == 3) {
                    size_t idx = (size_t)grow * 256 + gcol;
                    float x = v + bias[gcol];
                    out_b[idx] = fbf(0.5f * x * (1.f + erff(x * 0.70710678118654752f)));
                }
            }
}

// ---------------- dt head ----------------
__global__ __launch_bounds__(256) void dt_k(const unsigned short* __restrict__ u,
                                            const unsigned short* __restrict__ W,
                                            const float* __restrict__ dtb,
                                            float* __restrict__ dts) {
    int id = blockIdx.x * 256 + threadIdx.x;
    int t = id >> 3, h = id & 7;
    const unsigned short* ur = u + (size_t)t * 256;
    const unsigned short* wr = W + (size_t)(1280 + h) * 256;
    float acc = 0.f;
    for (int k = 0; k < 256; k += 8) {
        u16x8 uv = *(const u16x8*)&ur[k];
        u16x8 wv = *(const u16x8*)&wr[k];
        #pragma unroll
        for (int i = 0; i < 8; i++) acc += bfb(uv[i]) * bfb(wv[i]);
    }
    acc += dtb[h];
    dts[id] = acc > 20.f ? acc : log1pf(expf(acc));
}

// ---------------- causal depthwise conv4 + bias + silu, IN-PLACE over xbc ----------------
__global__ __launch_bounds__(256) void conv_k(unsigned short* xbc,
                                              const float* __restrict__ cw,
                                              const float* __restrict__ cb) {
    int b = blockIdx.y;
    int c0 = blockIdx.x * 64;
    int tid = threadIdx.x;
    int c = tid & 63;
    int rq = tid >> 6;               // 0..3
    __shared__ unsigned short sraw[131][72];
    int ca = c0 + c;
    float w0 = cw[ca * 4 + 0], w1 = cw[ca * 4 + 1];
    float w2 = cw[ca * 4 + 2], w3 = cw[ca * 4 + 3];
    float bias = cb[ca];
    unsigned short carry_u = 0;

    for (int t0 = 0; t0 < 512; t0 += 128) {
        __syncthreads();
        if (tid < 192) sraw[rq][c] = carry_u;
        for (int idx = tid; idx < 1024; idx += 256) {
            int lt = idx >> 3, cg = idx & 7;
            *(u16x8*)&sraw[3 + lt][cg * 8] =
                *(const u16x8*)&xbc[((size_t)(b * 512 + t0 + lt)) * 768 + c0 + cg * 8];
        }
        __syncthreads();
        if (tid < 192) carry_u = sraw[128 + rq][c];
        #pragma unroll 4
        for (int i = 0; i < 32; i++) {
            int lt = rq + 4 * i;
            float acc = bias
                + bfb(sraw[lt + 0][c]) * w0
                + bfb(sraw[lt + 1][c]) * w1
                + bfb(sraw[lt + 2][c]) * w2
                + bfb(sraw[lt + 3][c]) * w3;
            acc = acc / (1.f + expf(-acc));
            xbc[((size_t)(b * 512 + t0 + lt)) * 768 + c0 + c] = fbf(acc);
        }
    }
}

// ---------------- SSM scan v2: 1024 blocks = (batch, head, p-half) ----------------
// 512 threads = p'(32) x g(16); each thread owns 8 states of one p row.
// B/C/x converted to f32 ONCE at staging (kills 32 converts/lane/step).
// LDS 36.3KB -> 4 blocks/CU -> full occupancy.
__global__ __launch_bounds__(512) void scan_k(const unsigned short* __restrict__ xc,
                                              const float* __restrict__ dts,
                                              const float* __restrict__ A_log,
                                              const float* __restrict__ D_param,
                                              unsigned short* __restrict__ y) {
    int blk = blockIdx.x;
    int b   = blk >> 4;
    int rem = blk & 15;
    int h   = rem >> 1;
    int ph  = rem & 1;           // which half of headdim
    int tid = threadIdx.x;
    int pl  = tid >> 4;          // 0..31
    int g   = tid & 15;          // 0..15 (8 states each)
    __shared__ float sB[32][128];
    __shared__ float sC[32][128];
    __shared__ float sx[32][32];
    __shared__ float sdt[32];
    __shared__ float sdA[32];
    float A_h = -expf(A_log[h]);
    float D_h = D_param[h];
    float hr[8];
    #pragma unroll
    for (int i = 0; i < 8; i++) hr[i] = 0.f;

    for (int tc = 0; tc < 512; tc += 32) {
        __syncthreads();
        {   // stage B,C: 32 tok x 128 ch; one u16x8 pair per thread
            int lt = tid >> 4, c8 = (tid & 15) << 3;
            size_t tok = (size_t)b * 512 + tc + lt;
            u16x8 bv = *(const u16x8*)&xc[tok * 768 + 512 + c8];
            u16x8 cv = *(const u16x8*)&xc[tok * 768 + 640 + c8];
            #pragma unroll
            for (int j = 0; j < 8; j++) { sB[lt][c8 + j] = bfb(bv[j]); sC[lt][c8 + j] = bfb(cv[j]); }
        }
        {   // stage x: 32 tok x 32 p (this half); 2 elems per thread
            #pragma unroll
            for (int rep = 0; rep < 2; rep++) {
                int idx = tid + rep * 512;
                int lt = idx >> 5, px = idx & 31;
                size_t tok = (size_t)b * 512 + tc + lt;
                sx[lt][px] = bfb(xc[tok * 768 + h * 64 + ph * 32 + px]);
            }
        }
        if (tid < 32) {
            float dtv = dts[((size_t)b * 512 + tc + tid) * 8 + h];
            sdt[tid] = dtv;
            sdA[tid] = expf(dtv * A_h);
        }
        __syncthreads();

        #pragma unroll 2
        for (int lt = 0; lt < 32; ++lt) {
            float dtv = sdt[lt];
            float dA  = sdA[lt];
            float xv  = sx[lt][pl];
            float dtx = dtv * xv;
            f32x4 b0 = *(const f32x4*)&sB[lt][g * 8];
            f32x4 b1 = *(const f32x4*)&sB[lt][g * 8 + 4];
            f32x4 c0 = *(const f32x4*)&sC[lt][g * 8];
            f32x4 c1 = *(const f32x4*)&sC[lt][g * 8 + 4];
            float ya = 0.f;
            #pragma unroll
            for (int i = 0; i < 4; i++) {
                hr[i] = hr[i] * dA + dtx * b0[i];
                ya += hr[i] * c0[i];
            }
            #pragma unroll
            for (int i = 0; i < 4; i++) {
                hr[4 + i] = hr[4 + i] * dA + dtx * b1[i];
                ya += hr[4 + i] * c1[i];
            }
            ya += __shfl_xor(ya, 1);
            ya += __shfl_xor(ya, 2);
            ya += __shfl_xor(ya, 4);
            ya += __shfl_xor(ya, 8);
            if (g == 0) {
                size_t tok = (size_t)b * 512 + tc + lt;
                y[tok * 512 + h * 64 + ph * 32 + pl] = fbf(ya + D_h * xv);
            }
        }
    }
}

// ---------------- gate (y * silu(zg)) + RMSNorm * w -> bf16 ----------------
__global__ __launch_bounds__(256) void gate_k(const unsigned short* __restrict__ y,
                                              const unsigned short* __restrict__ zg,
                                              const float* __restrict__ nw,
                                              unsigned short* __restrict__ yn) {
    int tok = blockIdx.x, tid = threadIdx.x;
    size_t base = (size_t)tok * 512;
    float gv[2];
    float q = 0.f;
    #pragma unroll
    for (int j = 0; j < 2; j++) {
        int c = tid + j * 256;
        float yy = bfb(y[base + c]);
        float zz = bfb(zg[base + c]);
        float s = zz / (1.f + expf(-zz));
        float t = yy * s;
        gv[j] = t;
        q += t * t;
    }
    __shared__ float sm[4];
    #pragma unroll
    for (int o = 32; o; o >>= 1) q += __shfl_down(q, o);
    if ((tid & 63) == 0) sm[tid >> 6] = q;
    __syncthreads();
    float ms = (sm[0] + sm[1] + sm[2] + sm[3]) * (1.f / 512.f);
    float r = rsqrtf(ms + LN_EPS);
    #pragma unroll
    for (int j = 0; j < 2; j++) {
        int c = tid + j * 256;
        yn[base + c] = fbf(gv[j] * r * nw[c]);
    }
}

extern "C" void kernel_launch(void* const* d_in, const int* in_sizes, int n_in,
                              void* d_out, int out_size, void* d_ws, size_t ws_size,
                              hipStream_t stream) {
    if (n_in < 22) return;
    static const int setup_sizes[22] = {8388608,256,256,329728,3072,768,8,8,8,512,
                                        131072,256,65536,256,256,256,256,65536,256,256,65536,256};
    for (int i = 0; i < 22; i++) if (in_sizes[i] != setup_sizes[i]) return;

    const float* z      = (const float*)d_in[0];
    const float* ln1w   = (const float*)d_in[1];
    const float* ln1b   = (const float*)d_in[2];
    const float* inW    = (const float*)d_in[3];
    const float* convw  = (const float*)d_in[4];
    const float* convb  = (const float*)d_in[5];
    const float* dtb    = (const float*)d_in[6];
    const float* Alog   = (const float*)d_in[7];
    const float* Dp     = (const float*)d_in[8];
    const float* normw  = (const float*)d_in[9];
    const float* outW   = (const float*)d_in[10];
    const float* ffg    = (const float*)d_in[11];
    const float* ffv    = (const float*)d_in[12];
    const float* ffb    = (const float*)d_in[13];
    const float* ln2w   = (const float*)d_in[14];
    const float* ln2b   = (const float*)d_in[15];
    const float* fc1g   = (const float*)d_in[16];
    const float* fc1v   = (const float*)d_in[17];
    const float* fc1b   = (const float*)d_in[18];
    const float* fc2g   = (const float*)d_in[19];
    const float* fc2v   = (const float*)d_in[20];
    const float* fc2b   = (const float*)d_in[21];
    float* out = (float*)d_out;
    (void)out_size;

    char* ws = (char*)d_ws;
    const size_t SLOT_A = (size_t)NTOK * 768 * 2;
    const size_t SLOT_B = (size_t)NTOK * 512 * 2;
    const size_t SLOT_C = (size_t)NTOK * 512 * 2;
    const size_t SLOT_D = (size_t)NTOK * 256 * 2;
    const size_t SLOT_E = (size_t)NTOK * 8 * 4;
    const size_t SLOT_W = (size_t)256 * 256 * 2;
    const size_t SLOT_WI = (size_t)1288 * 256 * 2;
    const size_t SLOT_WO = (size_t)256 * 512 * 2;
    char* pA = ws;
    char* pB = pA + SLOT_A;
    char* pC = pB + SLOT_B;
    char* pD = pC + SLOT_C;
    char* pE = pD + SLOT_D;
    char* pW = pE + SLOT_E;
    char* pWI = pW + 3 * SLOT_W;
    char* pWO = pWI + SLOT_WI;
    size_t need = SLOT_A + SLOT_B + SLOT_C + SLOT_D + SLOT_E + 3 * SLOT_W + SLOT_WI + SLOT_WO;
    if (ws_size < need) return;

    unsigned short* xbc = (unsigned short*)pA;
    unsigned short* yn  = (unsigned short*)pA;
    unsigned short* t2  = (unsigned short*)(pA + (size_t)NTOK * 512 * 2);
    unsigned short* y   = (unsigned short*)pB;
    float*          z2  = (float*)pB;
    unsigned short* zgb = (unsigned short*)pC;
    unsigned short* u   = (unsigned short*)pD;
    unsigned short* m1  = (unsigned short*)pD;
    unsigned short* h1  = (unsigned short*)pD;
    float*          dts = (float*)pE;
    unsigned short* wff  = (unsigned short*)pW;
    unsigned short* wfc1 = (unsigned short*)(pW + SLOT_W);
    unsigned short* wfc2 = (unsigned short*)(pW + 2 * SLOT_W);
    unsigned short* inWb = (unsigned short*)pWI;
    unsigned short* outWb = (unsigned short*)pWO;

    cvt_k<<<(1288 * 256 + 255) / 256, 256, 0, stream>>>(inW, inWb, 1288 * 256);
    cvt_k<<<(256 * 512 + 255) / 256, 256, 0, stream>>>(outW, outWb, 256 * 512);
    wnorm_k<<<256, 256, 0, stream>>>(ffg,  ffv,  wff);
    wnorm_k<<<256, 256, 0, stream>>>(fc1g, fc1v, wfc1);
    wnorm_k<<<256, 256, 0, stream>>>(fc2g, fc2v, wfc2);
    ln_k<<<NTOK, 256, 0, stream>>>(z, ln1w, ln1b, u);
    gemm_k<1><<<dim3(256, 10), 256, 0, stream>>>(u, inWb, 256, 1280,
                                                 zgb, nullptr, nullptr, nullptr, xbc);
    dt_k<<<NTOK * 8 / 256, 256, 0, stream>>>(u, inWb, dtb, dts);
    conv_k<<<dim3(12, 64), 256, 0, stream>>>(xbc, convw, convb);
    scan_k<<<NBATCH * NHEADS * 2, 512, 0, stream>>>(xbc, dts, Alog, Dp, y);
    gate_k<<<NTOK, 256, 0, stream>>>(y, zgb, normw, yn);
    gemm_k<0><<<dim3(256, 2), 256, 0, stream>>>(yn, outWb, 512, 256,
                                                m1, nullptr, nullptr, nullptr, nullptr);
    gemm_k<2><<<dim3(256, 2), 256, 0, stream>>>(m1, wff, 256, 256,
                                                nullptr, z2, ffb, z, nullptr);
    ln_k<<<NTOK, 256, 0, stream>>>(z2, ln2w, ln2b, t2);
    gemm_k<3><<<dim3(256, 2), 256, 0, stream>>>(t2, wfc1, 256, 256,
                                                h1, nullptr, fc1b, nullptr, nullptr);
    gemm_k<2><<<dim3(256, 2), 256, 0, stream>>>(h1, wfc2, 256, 256,
                                                nullptr, out, fc2b, z2, nullptr);
}

// Round 11
// 625.878 us; speedup vs baseline: 1.1331x; 1.1331x over previous
//
#include <hip/hip_runtime.h>
#include <stdint.h>
#include <math.h>

#define EMB       256
#define D_INNER   512
#define HEADDIM   64
#define NHEADS    8
#define DSTATE    128
#define DCONV     4
#define CONV_DIM  768
#define LN_EPS    1e-5f
#define NBATCH    64
#define SEQLEN    512
#define NTOK      (NBATCH*SEQLEN)   // 32768

typedef __attribute__((ext_vector_type(8))) short          short8;
typedef __attribute__((ext_vector_type(8))) unsigned short u16x8;
typedef __attribute__((ext_vector_type(4))) float          f32x4;

__device__ __forceinline__ float bfb(unsigned short u) {
    union { unsigned int i; float f; } x; x.i = ((unsigned int)u) << 16; return x.f;
}
__device__ __forceinline__ unsigned short fbf(float f) {
    union { float f; unsigned int i; } x; x.f = f;
    unsigned int i = x.i;
    unsigned int lsb = (i >> 16) & 1u;
    i += 0x7fffu + lsb;
    return (unsigned short)(i >> 16);
}

// ---------------- f32 -> bf16 convert (weights) ----------------
__global__ __launch_bounds__(256) void cvt_k(const float* __restrict__ in,
                                             unsigned short* __restrict__ out, int n) {
    int i = blockIdx.x * 256 + threadIdx.x;
    if (i < n) out[i] = fbf(in[i]);
}

// ---------------- LayerNorm (256-wide), f32 in -> bf16 out ----------------
__global__ __launch_bounds__(256) void ln_k(const float* __restrict__ in,
                                            const float* __restrict__ w,
                                            const float* __restrict__ b,
                                            unsigned short* __restrict__ out) {
    int tok = blockIdx.x, tid = threadIdx.x;
    size_t idx = (size_t)tok * 256 + tid;
    float x = in[idx];
    __shared__ float sm[8];
    float s = x;
    #pragma unroll
    for (int o = 32; o; o >>= 1) s += __shfl_down(s, o);
    if ((tid & 63) == 0) sm[tid >> 6] = s;
    __syncthreads();
    float mean = (sm[0] + sm[1] + sm[2] + sm[3]) * (1.f / 256.f);
    float d = x - mean;
    float q = d * d;
    #pragma unroll
    for (int o = 32; o; o >>= 1) q += __shfl_down(q, o);
    if ((tid & 63) == 0) sm[4 + (tid >> 6)] = q;
    __syncthreads();
    float var = (sm[4] + sm[5] + sm[6] + sm[7]) * (1.f / 256.f);
    out[idx] = fbf(d * rsqrtf(var + LN_EPS) * w[tid] + b[tid]);
}

// ---------------- weight-norm: w[o][k] = g[o]*v[o][k]/||v[o]||, f32 -> bf16 ----------------
__global__ __launch_bounds__(256) void wnorm_k(const float* __restrict__ g,
                                               const float* __restrict__ v,
                                               unsigned short* __restrict__ wout) {
    int o = blockIdx.x, tid = threadIdx.x;
    float x = v[(size_t)o * 256 + tid];
    float q = x * x;
    __shared__ float sm[4];
    #pragma unroll
    for (int d = 32; d; d >>= 1) q += __shfl_down(q, d);
    if ((tid & 63) == 0) sm[tid >> 6] = q;
    __syncthreads();
    float tot = sm[0] + sm[1] + sm[2] + sm[3];
    float scale = g[o] * rsqrtf(tot);
    wout[(size_t)o * 256 + tid] = fbf(x * scale);
}

// ---------------- MFMA GEMM: C[M,N] = A[M,K] @ B[N,K]^T, 128x128 tile ----------------
// EPI: 0 plain->bf16 | 1 in_proj split (zg | xbc) | 2 bias+res_f32 -> f32 out | 3 bias+gelu -> bf16
#define BMT 128
#define BNT 128
#define BKT 32
template<int EPI>
__global__ __launch_bounds__(256) void gemm_k(const unsigned short* __restrict__ A,
                                              const unsigned short* __restrict__ Bw,
                                              int K, int N,
                                              unsigned short* __restrict__ out_b,
                                              float* __restrict__ out_f,
                                              const float* __restrict__ bias,
                                              const float* __restrict__ res_f,
                                              unsigned short* __restrict__ out2_b) {
    __shared__ unsigned short As[BMT][BKT + 8];
    __shared__ unsigned short Bs[BNT][BKT + 8];
    int tid = threadIdx.x;
    int bm = blockIdx.x, bn = blockIdx.y;
    int lane = tid & 63, w = tid >> 6;
    int wr = w >> 1, wc = w & 1;
    int fr = lane & 15, fq = lane >> 4;
    f32x4 acc[4][4];
    #pragma unroll
    for (int m = 0; m < 4; m++)
        #pragma unroll
        for (int n = 0; n < 4; n++)
            #pragma unroll
            for (int r = 0; r < 4; r++) acc[m][n][r] = 0.f;

    int r0 = tid >> 2;           // 0..63
    int kc = (tid & 3) << 3;     // 0,8,16,24
    for (int k0 = 0; k0 < K; k0 += BKT) {
        __syncthreads();
        *(u16x8*)&As[r0][kc]      = *(const u16x8*)&A[(size_t)(bm * BMT + r0) * K + k0 + kc];
        *(u16x8*)&As[r0 + 64][kc] = *(const u16x8*)&A[(size_t)(bm * BMT + r0 + 64) * K + k0 + kc];
        *(u16x8*)&Bs[r0][kc]      = *(const u16x8*)&Bw[(size_t)(bn * BNT + r0) * K + k0 + kc];
        *(u16x8*)&Bs[r0 + 64][kc] = *(const u16x8*)&Bw[(size_t)(bn * BNT + r0 + 64) * K + k0 + kc];
        __syncthreads();
        short8 af[4], bf_[4];
        #pragma unroll
        for (int m = 0; m < 4; m++) af[m] = *(const short8*)&As[wr * 64 + m * 16 + fr][fq * 8];
        #pragma unroll
        for (int n = 0; n < 4; n++) bf_[n] = *(const short8*)&Bs[wc * 64 + n * 16 + fr][fq * 8];
        #pragma unroll
        for (int m = 0; m < 4; m++)
            #pragma unroll
            for (int n = 0; n < 4; n++)
                acc[m][n] = __builtin_amdgcn_mfma_f32_16x16x32_bf16(af[m], bf_[n], acc[m][n], 0, 0, 0);
    }

    #pragma unroll
    for (int m = 0; m < 4; m++)
        #pragma unroll
        for (int n = 0; n < 4; n++)
            #pragma unroll
            for (int r = 0; r < 4; r++) {
                int grow = bm * BMT + wr * 64 + m * 16 + fq * 4 + r;
                int gcol = bn * BNT + wc * 64 + n * 16 + fr;
                float v = acc[m][n][r];
                if (EPI == 0) {
                    out_b[(size_t)grow * N + gcol] = fbf(v);
                } else if (EPI == 1) {
                    if (gcol < 512) out_b[(size_t)grow * 512 + gcol] = fbf(v);
                    else            out2_b[(size_t)grow * 768 + (gcol - 512)] = fbf(v);
                } else if (EPI == 2) {
                    size_t idx = (size_t)grow * 256 + gcol;
                    out_f[idx] = res_f[idx] + v + bias[gcol];
                } else if (EPI == 3) {
                    size_t idx = (size_t)grow * 256 + gcol;
                    float x = v + bias[gcol];
                    out_b[idx] = fbf(0.5f * x * (1.f + erff(x * 0.70710678118654752f)));
                }
            }
}

// ---------------- dt head ----------------
__global__ __launch_bounds__(256) void dt_k(const unsigned short* __restrict__ u,
                                            const unsigned short* __restrict__ W,
                                            const float* __restrict__ dtb,
                                            float* __restrict__ dts) {
    int id = blockIdx.x * 256 + threadIdx.x;
    int t = id >> 3, h = id & 7;
    const unsigned short* ur = u + (size_t)t * 256;
    const unsigned short* wr = W + (size_t)(1280 + h) * 256;
    float acc = 0.f;
    for (int k = 0; k < 256; k += 8) {
        u16x8 uv = *(const u16x8*)&ur[k];
        u16x8 wv = *(const u16x8*)&wr[k];
        #pragma unroll
        for (int i = 0; i < 8; i++) acc += bfb(uv[i]) * bfb(wv[i]);
    }
    acc += dtb[h];
    dts[id] = acc > 20.f ? acc : log1pf(expf(acc));
}

// ---------------- causal depthwise conv4 + bias + silu, IN-PLACE over xbc ----------------
__global__ __launch_bounds__(256) void conv_k(unsigned short* xbc,
                                              const float* __restrict__ cw,
                                              const float* __restrict__ cb) {
    int b = blockIdx.y;
    int c0 = blockIdx.x * 64;
    int tid = threadIdx.x;
    int c = tid & 63;
    int rq = tid >> 6;               // 0..3
    __shared__ unsigned short sraw[131][72];
    int ca = c0 + c;
    float w0 = cw[ca * 4 + 0], w1 = cw[ca * 4 + 1];
    float w2 = cw[ca * 4 + 2], w3 = cw[ca * 4 + 3];
    float bias = cb[ca];
    unsigned short carry_u = 0;

    for (int t0 = 0; t0 < 512; t0 += 128) {
        __syncthreads();
        if (tid < 192) sraw[rq][c] = carry_u;
        for (int idx = tid; idx < 1024; idx += 256) {
            int lt = idx >> 3, cg = idx & 7;
            *(u16x8*)&sraw[3 + lt][cg * 8] =
                *(const u16x8*)&xbc[((size_t)(b * 512 + t0 + lt)) * 768 + c0 + cg * 8];
        }
        __syncthreads();
        if (tid < 192) carry_u = sraw[128 + rq][c];
        #pragma unroll 4
        for (int i = 0; i < 32; i++) {
            int lt = rq + 4 * i;
            float acc = bias
                + bfb(sraw[lt + 0][c]) * w0
                + bfb(sraw[lt + 1][c]) * w1
                + bfb(sraw[lt + 2][c]) * w2
                + bfb(sraw[lt + 3][c]) * w3;
            acc = acc / (1.f + expf(-acc));
            xbc[((size_t)(b * 512 + t0 + lt)) * 768 + c0 + c] = fbf(acc);
        }
    }
}

// ---------------- SSM scan v3: 1024 blocks = (batch, head, p-half) ----------------
// 512 threads = p'(32) x g(16); 8 states/thread. B/C staged as f32 in SPLIT-PAIR
// layout: group g states 0-3 at [lt][g*4], states 4-7 at [lt][64+g*4], so both
// staging writes and step reads are f32x4 @ 16B stride across the 16 g-lanes
// (256B contiguous coverage = the round-9-measured 0-conflict pattern).
__global__ __launch_bounds__(512) void scan_k(const unsigned short* __restrict__ xc,
                                              const float* __restrict__ dts,
                                              const float* __restrict__ A_log,
                                              const float* __restrict__ D_param,
                                              unsigned short* __restrict__ y) {
    int blk = blockIdx.x;
    int b   = blk >> 4;
    int rem = blk & 15;
    int h   = rem >> 1;
    int ph  = rem & 1;           // which half of headdim
    int tid = threadIdx.x;
    int pl  = tid >> 4;          // 0..31
    int g   = tid & 15;          // 0..15 (8 states each)
    __shared__ float sB[32][128];
    __shared__ float sC[32][128];
    __shared__ float sx[32][32];
    __shared__ float sdt[32];
    __shared__ float sdA[32];
    float A_h = -expf(A_log[h]);
    float D_h = D_param[h];
    float hr[8];
    #pragma unroll
    for (int i = 0; i < 8; i++) hr[i] = 0.f;

    for (int tc = 0; tc < 512; tc += 32) {
        __syncthreads();
        {   // stage B,C in split-pair layout: 4x f32x4 store per thread, 16B lane stride
            int lt = tid >> 4, gq = tid & 15;
            size_t tok = (size_t)b * 512 + tc + lt;
            u16x8 bv = *(const u16x8*)&xc[tok * 768 + 512 + gq * 8];
            u16x8 cv = *(const u16x8*)&xc[tok * 768 + 640 + gq * 8];
            f32x4 blo, bhi, clo, chi;
            #pragma unroll
            for (int j = 0; j < 4; j++) {
                blo[j] = bfb(bv[j]);     bhi[j] = bfb(bv[4 + j]);
                clo[j] = bfb(cv[j]);     chi[j] = bfb(cv[4 + j]);
            }
            *(f32x4*)&sB[lt][gq * 4]      = blo;
            *(f32x4*)&sB[lt][64 + gq * 4] = bhi;
            *(f32x4*)&sC[lt][gq * 4]      = clo;
            *(f32x4*)&sC[lt][64 + gq * 4] = chi;
        }
        {   // stage x: 32 tok x 32 p (this half); 2 elems per thread
            #pragma unroll
            for (int rep = 0; rep < 2; rep++) {
                int idx = tid + rep * 512;
                int lt = idx >> 5, px = idx & 31;
                size_t tok = (size_t)b * 512 + tc + lt;
                sx[lt][px] = bfb(xc[tok * 768 + h * 64 + ph * 32 + px]);
            }
        }
        if (tid < 32) {
            float dtv = dts[((size_t)b * 512 + tc + tid) * 8 + h];
            sdt[tid] = dtv;
            sdA[tid] = expf(dtv * A_h);
        }
        __syncthreads();

        #pragma unroll 2
        for (int lt = 0; lt < 32; ++lt) {
            float dtv = sdt[lt];
            float dA  = sdA[lt];
            float xv  = sx[lt][pl];
            float dtx = dtv * xv;
            f32x4 b0 = *(const f32x4*)&sB[lt][g * 4];        // states g*8+0..3
            f32x4 b1 = *(const f32x4*)&sB[lt][64 + g * 4];   // states g*8+4..7
            f32x4 c0 = *(const f32x4*)&sC[lt][g * 4];
            f32x4 c1 = *(const f32x4*)&sC[lt][64 + g * 4];
            float ya = 0.f;
            #pragma unroll
            for (int i = 0; i < 4; i++) {
                hr[i] = hr[i] * dA + dtx * b0[i];
                ya += hr[i] * c0[i];
            }
            #pragma unroll
            for (int i = 0; i < 4; i++) {
                hr[4 + i] = hr[4 + i] * dA + dtx * b1[i];
                ya += hr[4 + i] * c1[i];
            }
            ya += __shfl_xor(ya, 1);
            ya += __shfl_xor(ya, 2);
            ya += __shfl_xor(ya, 4);
            ya += __shfl_xor(ya, 8);
            if (g == 0) {
                size_t tok = (size_t)b * 512 + tc + lt;
                y[tok * 512 + h * 64 + ph * 32 + pl] = fbf(ya + D_h * xv);
            }
        }
    }
}

// ---------------- gate (y * silu(zg)) + RMSNorm * w -> bf16 ----------------
__global__ __launch_bounds__(256) void gate_k(const unsigned short* __restrict__ y,
                                              const unsigned short* __restrict__ zg,
                                              const float* __restrict__ nw,
                                              unsigned short* __restrict__ yn) {
    int tok = blockIdx.x, tid = threadIdx.x;
    size_t base = (size_t)tok * 512;
    float gv[2];
    float q = 0.f;
    #pragma unroll
    for (int j = 0; j < 2; j++) {
        int c = tid + j * 256;
        float yy = bfb(y[base + c]);
        float zz = bfb(zg[base + c]);
        float s = zz / (1.f + expf(-zz));
        float t = yy * s;
        gv[j] = t;
        q += t * t;
    }
    __shared__ float sm[4];
    #pragma unroll
    for (int o = 32; o; o >>= 1) q += __shfl_down(q, o);
    if ((tid & 63) == 0) sm[tid >> 6] = q;
    __syncthreads();
    float ms = (sm[0] + sm[1] + sm[2] + sm[3]) * (1.f / 512.f);
    float r = rsqrtf(ms + LN_EPS);
    #pragma unroll
    for (int j = 0; j < 2; j++) {
        int c = tid + j * 256;
        yn[base + c] = fbf(gv[j] * r * nw[c]);
    }
}

extern "C" void kernel_launch(void* const* d_in, const int* in_sizes, int n_in,
                              void* d_out, int out_size, void* d_ws, size_t ws_size,
                              hipStream_t stream) {
    if (n_in < 22) return;
    static const int setup_sizes[22] = {8388608,256,256,329728,3072,768,8,8,8,512,
                                        131072,256,65536,256,256,256,256,65536,256,256,65536,256};
    for (int i = 0; i < 22; i++) if (in_sizes[i] != setup_sizes[i]) return;

    const float* z      = (const float*)d_in[0];
    const float* ln1w   = (const float*)d_in[1];
    const float* ln1b   = (const float*)d_in[2];
    const float* inW    = (const float*)d_in[3];
    const float* convw  = (const float*)d_in[4];
    const float* convb  = (const float*)d_in[5];
    const float* dtb    = (const float*)d_in[6];
    const float* Alog   = (const float*)d_in[7];
    const float* Dp     = (const float*)d_in[8];
    const float* normw  = (const float*)d_in[9];
    const float* outW   = (const float*)d_in[10];
    const float* ffg    = (const float*)d_in[11];
    const float* ffv    = (const float*)d_in[12];
    const float* ffb    = (const float*)d_in[13];
    const float* ln2w   = (const float*)d_in[14];
    const float* ln2b   = (const float*)d_in[15];
    const float* fc1g   = (const float*)d_in[16];
    const float* fc1v   = (const float*)d_in[17];
    const float* fc1b   = (const float*)d_in[18];
    const float* fc2g   = (const float*)d_in[19];
    const float* fc2v   = (const float*)d_in[20];
    const float* fc2b   = (const float*)d_in[21];
    float* out = (float*)d_out;
    (void)out_size;

    char* ws = (char*)d_ws;
    const size_t SLOT_A = (size_t)NTOK * 768 * 2;
    const size_t SLOT_B = (size_t)NTOK * 512 * 2;
    const size_t SLOT_C = (size_t)NTOK * 512 * 2;
    const size_t SLOT_D = (size_t)NTOK * 256 * 2;
    const size_t SLOT_E = (size_t)NTOK * 8 * 4;
    const size_t SLOT_W = (size_t)256 * 256 * 2;
    const size_t SLOT_WI = (size_t)1288 * 256 * 2;
    const size_t SLOT_WO = (size_t)256 * 512 * 2;
    char* pA = ws;
    char* pB = pA + SLOT_A;
    char* pC = pB + SLOT_B;
    char* pD = pC + SLOT_C;
    char* pE = pD + SLOT_D;
    char* pW = pE + SLOT_E;
    char* pWI = pW + 3 * SLOT_W;
    char* pWO = pWI + SLOT_WI;
    size_t need = SLOT_A + SLOT_B + SLOT_C + SLOT_D + SLOT_E + 3 * SLOT_W + SLOT_WI + SLOT_WO;
    if (ws_size < need) return;

    unsigned short* xbc = (unsigned short*)pA;
    unsigned short* yn  = (unsigned short*)pA;
    unsigned short* t2  = (unsigned short*)(pA + (size_t)NTOK * 512 * 2);
    unsigned short* y   = (unsigned short*)pB;
    float*          z2  = (float*)pB;
    unsigned short* zgb = (unsigned short*)pC;
    unsigned short* u   = (unsigned short*)pD;
    unsigned short* m1  = (unsigned short*)pD;
    unsigned short* h1  = (unsigned short*)pD;
    float*          dts = (float*)pE;
    unsigned short* wff  = (unsigned short*)pW;
    unsigned short* wfc1 = (unsigned short*)(pW + SLOT_W);
    unsigned short* wfc2 = (unsigned short*)(pW + 2 * SLOT_W);
    unsigned short* inWb = (unsigned short*)pWI;
    unsigned short* outWb = (unsigned short*)pWO;

    cvt_k<<<(1288 * 256 + 255) / 256, 256, 0, stream>>>(inW, inWb, 1288 * 256);
    cvt_k<<<(256 * 512 + 255) / 256, 256, 0, stream>>>(outW, outWb, 256 * 512);
    wnorm_k<<<256, 256, 0, stream>>>(ffg,  ffv,  wff);
    wnorm_k<<<256, 256, 0, stream>>>(fc1g, fc1v, wfc1);
    wnorm_k<<<256, 256, 0, stream>>>(fc2g, fc2v, wfc2);
    ln_k<<<NTOK, 256, 0, stream>>>(z, ln1w, ln1b, u);
    gemm_k<1><<<dim3(256, 10), 256, 0, stream>>>(u, inWb, 256, 1280,
                                                 zgb, nullptr, nullptr, nullptr, xbc);
    dt_k<<<NTOK * 8 / 256, 256, 0, stream>>>(u, inWb, dtb, dts);
    conv_k<<<dim3(12, 64), 256, 0, stream>>>(xbc, convw, convb);
    scan_k<<<NBATCH * NHEADS * 2, 512, 0, stream>>>(xbc, dts, Alog, Dp, y);
    gate_k<<<NTOK, 256, 0, stream>>>(y, zgb, normw, yn);
    gemm_k<0><<<dim3(256, 2), 256, 0, stream>>>(yn, outWb, 512, 256,
                                                m1, nullptr, nullptr, nullptr, nullptr);
    gemm_k<2><<<dim3(256, 2), 256, 0, stream>>>(m1, wff, 256, 256,
                                                nullptr, z2, ffb, z, nullptr);
    ln_k<<<NTOK, 256, 0, stream>>>(z2, ln2w, ln2b, t2);
    gemm_k<3><<<dim3(256, 2), 256, 0, stream>>>(t2, wfc1, 256, 256,
                                                h1, nullptr, fc1b, nullptr, nullptr);
    gemm_k<2><<<dim3(256, 2), 256, 0, stream>>>(h1, wfc2, 256, 256,
                                                nullptr, out, fc2b, z2, nullptr);
}

// Round 12
// 346.984 us; speedup vs baseline: 2.0438x; 1.8038x over previous
//
#include <hip/hip_runtime.h>
#include <stdint.h>
#include <math.h>

#define EMB       256
#define D_INNER   512
#define HEADDIM   64
#define NHEADS    8
#define DSTATE    128
#define DCONV     4
#define CONV_DIM  768
#define LN_EPS    1e-5f
#define NBATCH    64
#define SEQLEN    512
#define NTOK      (NBATCH*SEQLEN)   // 32768

typedef __attribute__((ext_vector_type(8))) short          short8;
typedef __attribute__((ext_vector_type(8))) unsigned short u16x8;
typedef __attribute__((ext_vector_type(4))) float          f32x4;

__device__ __forceinline__ float bfb(unsigned short u) {
    union { unsigned int i; float f; } x; x.i = ((unsigned int)u) << 16; return x.f;
}
__device__ __forceinline__ unsigned short fbf(float f) {
    union { float f; unsigned int i; } x; x.f = f;
    unsigned int i = x.i;
    unsigned int lsb = (i >> 16) & 1u;
    i += 0x7fffu + lsb;
    return (unsigned short)(i >> 16);
}

// ---------------- f32 -> bf16 convert (weights) ----------------
__global__ __launch_bounds__(256) void cvt_k(const float* __restrict__ in,
                                             unsigned short* __restrict__ out, int n) {
    int i = blockIdx.x * 256 + threadIdx.x;
    if (i < n) out[i] = fbf(in[i]);
}

// ---------------- LayerNorm (256-wide), f32 in -> bf16 out ----------------
__global__ __launch_bounds__(256) void ln_k(const float* __restrict__ in,
                                            const float* __restrict__ w,
                                            const float* __restrict__ b,
                                            unsigned short* __restrict__ out) {
    int tok = blockIdx.x, tid = threadIdx.x;
    size_t idx = (size_t)tok * 256 + tid;
    float x = in[idx];
    __shared__ float sm[8];
    float s = x;
    #pragma unroll
    for (int o = 32; o; o >>= 1) s += __shfl_down(s, o);
    if ((tid & 63) == 0) sm[tid >> 6] = s;
    __syncthreads();
    float mean = (sm[0] + sm[1] + sm[2] + sm[3]) * (1.f / 256.f);
    float d = x - mean;
    float q = d * d;
    #pragma unroll
    for (int o = 32; o; o >>= 1) q += __shfl_down(q, o);
    if ((tid & 63) == 0) sm[4 + (tid >> 6)] = q;
    __syncthreads();
    float var = (sm[4] + sm[5] + sm[6] + sm[7]) * (1.f / 256.f);
    out[idx] = fbf(d * rsqrtf(var + LN_EPS) * w[tid] + b[tid]);
}

// ---------------- weight-norm ----------------
__global__ __launch_bounds__(256) void wnorm_k(const float* __restrict__ g,
                                               const float* __restrict__ v,
                                               unsigned short* __restrict__ wout) {
    int o = blockIdx.x, tid = threadIdx.x;
    float x = v[(size_t)o * 256 + tid];
    float q = x * x;
    __shared__ float sm[4];
    #pragma unroll
    for (int d = 32; d; d >>= 1) q += __shfl_down(q, d);
    if ((tid & 63) == 0) sm[tid >> 6] = q;
    __syncthreads();
    float tot = sm[0] + sm[1] + sm[2] + sm[3];
    float scale = g[o] * rsqrtf(tot);
    wout[(size_t)o * 256 + tid] = fbf(x * scale);
}

// ---------------- MFMA GEMM: C[M,N] = A[M,K] @ B[N,K]^T, 128x128 tile ----------------
#define BMT 128
#define BNT 128
#define BKT 32
template<int EPI>
__global__ __launch_bounds__(256) void gemm_k(const unsigned short* __restrict__ A,
                                              const unsigned short* __restrict__ Bw,
                                              int K, int N,
                                              unsigned short* __restrict__ out_b,
                                              float* __restrict__ out_f,
                                              const float* __restrict__ bias,
                                              const float* __restrict__ res_f,
                                              unsigned short* __restrict__ out2_b) {
    __shared__ unsigned short As[BMT][BKT + 8];
    __shared__ unsigned short Bs[BNT][BKT + 8];
    int tid = threadIdx.x;
    int bm = blockIdx.x, bn = blockIdx.y;
    int lane = tid & 63, w = tid >> 6;
    int wr = w >> 1, wc = w & 1;
    int fr = lane & 15, fq = lane >> 4;
    f32x4 acc[4][4];
    #pragma unroll
    for (int m = 0; m < 4; m++)
        #pragma unroll
        for (int n = 0; n < 4; n++)
            #pragma unroll
            for (int r = 0; r < 4; r++) acc[m][n][r] = 0.f;

    int r0 = tid >> 2;
    int kc = (tid & 3) << 3;
    for (int k0 = 0; k0 < K; k0 += BKT) {
        __syncthreads();
        *(u16x8*)&As[r0][kc]      = *(const u16x8*)&A[(size_t)(bm * BMT + r0) * K + k0 + kc];
        *(u16x8*)&As[r0 + 64][kc] = *(const u16x8*)&A[(size_t)(bm * BMT + r0 + 64) * K + k0 + kc];
        *(u16x8*)&Bs[r0][kc]      = *(const u16x8*)&Bw[(size_t)(bn * BNT + r0) * K + k0 + kc];
        *(u16x8*)&Bs[r0 + 64][kc] = *(const u16x8*)&Bw[(size_t)(bn * BNT + r0 + 64) * K + k0 + kc];
        __syncthreads();
        short8 af[4], bf_[4];
        #pragma unroll
        for (int m = 0; m < 4; m++) af[m] = *(const short8*)&As[wr * 64 + m * 16 + fr][fq * 8];
        #pragma unroll
        for (int n = 0; n < 4; n++) bf_[n] = *(const short8*)&Bs[wc * 64 + n * 16 + fr][fq * 8];
        #pragma unroll
        for (int m = 0; m < 4; m++)
            #pragma unroll
            for (int n = 0; n < 4; n++)
                acc[m][n] = __builtin_amdgcn_mfma_f32_16x16x32_bf16(af[m], bf_[n], acc[m][n], 0, 0, 0);
    }

    #pragma unroll
    for (int m = 0; m < 4; m++)
        #pragma unroll
        for (int n = 0; n < 4; n++)
            #pragma unroll
            for (int r = 0; r < 4; r++) {
                int grow = bm * BMT + wr * 64 + m * 16 + fq * 4 + r;
                int gcol = bn * BNT + wc * 64 + n * 16 + fr;
                float v = acc[m][n][r];
                if (EPI == 0) {
                    out_b[(size_t)grow * N + gcol] = fbf(v);
                } else if (EPI == 1) {
                    if (gcol < 512) out_b[(size_t)grow * 512 + gcol] = fbf(v);
                    else            out2_b[(size_t)grow * 768 + (gcol - 512)] = fbf(v);
                } else if (EPI == 2) {
                    size_t idx = (size_t)grow * 256 + gcol;
                    out_f[idx] = res_f[idx] + v + bias[gcol];
                } else if (EPI == 3) {
                    size_t idx = (size_t)grow * 256 + gcol;
                    float x = v + bias[gcol];
                    out_b[idx] = fbf(0.5f * x * (1.f + erff(x * 0.70710678118654752f)));
                }
            }
}

// ---------------- dt head ----------------
__global__ __launch_bounds__(256) void dt_k(const unsigned short* __restrict__ u,
                                            const unsigned short* __restrict__ W,
                                            const float* __restrict__ dtb,
                                            float* __restrict__ dts) {
    int id = blockIdx.x * 256 + threadIdx.x;
    int t = id >> 3, h = id & 7;
    const unsigned short* ur = u + (size_t)t * 256;
    const unsigned short* wr = W + (size_t)(1280 + h) * 256;
    float acc = 0.f;
    for (int k = 0; k < 256; k += 8) {
        u16x8 uv = *(const u16x8*)&ur[k];
        u16x8 wv = *(const u16x8*)&wr[k];
        #pragma unroll
        for (int i = 0; i < 8; i++) acc += bfb(uv[i]) * bfb(wv[i]);
    }
    acc += dtb[h];
    dts[id] = acc > 20.f ? acc : log1pf(expf(acc));
}

// ---------------- causal depthwise conv4 + bias + silu, IN-PLACE over xbc ----------------
__global__ __launch_bounds__(256) void conv_k(unsigned short* xbc,
                                              const float* __restrict__ cw,
                                              const float* __restrict__ cb) {
    int b = blockIdx.y;
    int c0 = blockIdx.x * 64;
    int tid = threadIdx.x;
    int c = tid & 63;
    int rq = tid >> 6;
    __shared__ unsigned short sraw[131][72];
    int ca = c0 + c;
    float w0 = cw[ca * 4 + 0], w1 = cw[ca * 4 + 1];
    float w2 = cw[ca * 4 + 2], w3 = cw[ca * 4 + 3];
    float bias = cb[ca];
    unsigned short carry_u = 0;

    for (int t0 = 0; t0 < 512; t0 += 128) {
        __syncthreads();
        if (tid < 192) sraw[rq][c] = carry_u;
        for (int idx = tid; idx < 1024; idx += 256) {
            int lt = idx >> 3, cg = idx & 7;
            *(u16x8*)&sraw[3 + lt][cg * 8] =
                *(const u16x8*)&xbc[((size_t)(b * 512 + t0 + lt)) * 768 + c0 + cg * 8];
        }
        __syncthreads();
        if (tid < 192) carry_u = sraw[128 + rq][c];
        #pragma unroll 4
        for (int i = 0; i < 32; i++) {
            int lt = rq + 4 * i;
            float acc = bias
                + bfb(sraw[lt + 0][c]) * w0
                + bfb(sraw[lt + 1][c]) * w1
                + bfb(sraw[lt + 2][c]) * w2
                + bfb(sraw[lt + 3][c]) * w3;
            acc = acc / (1.f + expf(-acc));
            xbc[((size_t)(b * 512 + t0 + lt)) * 768 + c0 + c] = fbf(acc);
        }
    }
}

// ---------------- SSD chunked-MFMA scan: 512 blocks = (b,h); 4 waves; 16 chunks of Q=32 ----
// Per chunk: G=C@B^T; LG=ET∘G; Y = LG@DX + e^{cum}∘(C@h^T) + D*x; h = e^{cumQ} h + DXW^T@B.
// h kept f32 in MFMA accumulators (wave w owns p-slice w*16..w*16+16).
#define CPAD 136   // rows of 128: stride 272B, 16B-aligned, uniform bank spread
#define TPAD 40    // rows of 32:  stride 80B,  16B-aligned, uniform bank spread
__global__ __launch_bounds__(256) void ssd_k(const unsigned short* __restrict__ xc,
                                             const float* __restrict__ dts,
                                             const float* __restrict__ A_log,
                                             const float* __restrict__ D_param,
                                             unsigned short* __restrict__ y) {
    __shared__ unsigned short Ct[32][CPAD];
    __shared__ unsigned short Bt[32][CPAD];
    __shared__ unsigned short BtT[128][TPAD];
    __shared__ unsigned short XT[64][TPAD];
    __shared__ unsigned short DXT[64][TPAD];
    __shared__ unsigned short DXWT[64][TPAD];
    __shared__ unsigned short LG[32][TPAD];
    __shared__ unsigned short hB[64][CPAD];
    __shared__ unsigned short Yb[32][72];
    __shared__ float scum[32], sdt2[32], sEC[32];
    __shared__ float sET[32][36];

    int bh = blockIdx.x;
    int b = bh >> 3, h = bh & 7;
    int tid = threadIdx.x;
    int w = tid >> 6;
    int lane = tid & 63;
    int fr = lane & 15, fq = lane >> 4;

    float A_h = -expf(A_log[h]);
    float D_h = D_param[h];

    f32x4 hacc[8];
    #pragma unroll
    for (int nf = 0; nf < 8; nf++)
        #pragma unroll
        for (int r = 0; r < 4; r++) hacc[nf][r] = 0.f;

    int t  = tid >> 3;          // 0..31 staging row
    int e8 = tid & 7;           // 0..7 staging column group

    for (int c = 0; c < 16; ++c) {
        size_t tok0 = (size_t)b * 512 + c * 32;
        // ---- Phase A: raw staging + cum prefix ----
        u16x8 bv0, bv1, cv0, cv1, xv;
        {
            const unsigned short* row = &xc[(tok0 + t) * 768];
            bv0 = *(const u16x8*)&row[512 + e8 * 16];
            bv1 = *(const u16x8*)&row[512 + e8 * 16 + 8];
            cv0 = *(const u16x8*)&row[640 + e8 * 16];
            cv1 = *(const u16x8*)&row[640 + e8 * 16 + 8];
            xv  = *(const u16x8*)&row[h * 64 + e8 * 8];
        }
        *(u16x8*)&Ct[t][e8 * 16]     = cv0;
        *(u16x8*)&Ct[t][e8 * 16 + 8] = cv1;
        *(u16x8*)&Bt[t][e8 * 16]     = bv0;
        *(u16x8*)&Bt[t][e8 * 16 + 8] = bv1;
        #pragma unroll
        for (int j = 0; j < 8; j++) {
            BtT[e8 * 16 + j][t]     = bv0[j];
            BtT[e8 * 16 + 8 + j][t] = bv1[j];
            XT[e8 * 8 + j][t]       = xv[j];
        }
        if (tid < 32) {
            float dtv = dts[(tok0 + tid) * 8 + h];
            sdt2[tid] = dtv;
            float la = dtv * A_h;
            #pragma unroll
            for (int d = 1; d < 32; d <<= 1) {
                float up = __shfl_up(la, d);
                if (lane >= d) la += up;
            }
            scum[tid] = la;
        }
        __syncthreads();
        float cumQ = scum[31];
        // ---- Phase B: weighted staging + h snapshot ----
        if (tid < 32) sEC[tid] = expf(scum[tid]);
        {
            float dtv = sdt2[t];
            float wgt = expf(cumQ - scum[t]);
            #pragma unroll
            for (int j = 0; j < 8; j++) {
                float dtx = dtv * bfb(xv[j]);
                DXT[e8 * 8 + j][t]  = fbf(dtx);
                DXWT[e8 * 8 + j][t] = fbf(wgt * dtx);
            }
        }
        #pragma unroll
        for (int k = 0; k < 4; k++) {
            int idx = tid * 4 + k;
            int tt = idx >> 5, tq = idx & 31;
            sET[tt][tq] = (tq <= tt) ? expf(scum[tt] - scum[tq]) : 0.f;
        }
        #pragma unroll
        for (int nf = 0; nf < 8; nf++)
            #pragma unroll
            for (int r = 0; r < 4; r++)
                hB[w * 16 + fq * 4 + r][nf * 16 + fr] = fbf(hacc[nf][r]);
        __syncthreads();
        // ---- Phase C: wave 0 computes LG = ET ∘ (C @ B^T) ----
        if (w == 0) {
            f32x4 g[2][2];
            #pragma unroll
            for (int m = 0; m < 2; m++)
                #pragma unroll
                for (int n = 0; n < 2; n++)
                    #pragma unroll
                    for (int r = 0; r < 4; r++) g[m][n][r] = 0.f;
            #pragma unroll
            for (int ks = 0; ks < 4; ks++) {
                short8 ca0 = *(const short8*)&Ct[fr][ks * 32 + fq * 8];
                short8 ca1 = *(const short8*)&Ct[16 + fr][ks * 32 + fq * 8];
                short8 bb0 = *(const short8*)&Bt[fr][ks * 32 + fq * 8];
                short8 bb1 = *(const short8*)&Bt[16 + fr][ks * 32 + fq * 8];
                g[0][0] = __builtin_amdgcn_mfma_f32_16x16x32_bf16(ca0, bb0, g[0][0], 0, 0, 0);
                g[0][1] = __builtin_amdgcn_mfma_f32_16x16x32_bf16(ca0, bb1, g[0][1], 0, 0, 0);
                g[1][0] = __builtin_amdgcn_mfma_f32_16x16x32_bf16(ca1, bb0, g[1][0], 0, 0, 0);
                g[1][1] = __builtin_amdgcn_mfma_f32_16x16x32_bf16(ca1, bb1, g[1][1], 0, 0, 0);
            }
            #pragma unroll
            for (int m = 0; m < 2; m++)
                #pragma unroll
                for (int nf = 0; nf < 2; nf++)
                    #pragma unroll
                    for (int r = 0; r < 4; r++) {
                        int tt = m * 16 + fq * 4 + r;
                        int tq = nf * 16 + fr;
                        LG[tt][tq] = fbf(g[m][nf][r] * sET[tt][tq]);
                    }
        }
        __syncthreads();
        // ---- Phase D: Y and h update ----
        f32x4 Yi[2];
        #pragma unroll
        for (int m = 0; m < 2; m++)
            #pragma unroll
            for (int r = 0; r < 4; r++) Yi[m][r] = 0.f;
        // inter: C @ h_prev^T (then row-scale by e^{cum_t})
        #pragma unroll
        for (int ks = 0; ks < 4; ks++) {
            short8 a0 = *(const short8*)&Ct[fr][ks * 32 + fq * 8];
            short8 a1 = *(const short8*)&Ct[16 + fr][ks * 32 + fq * 8];
            short8 hb = *(const short8*)&hB[w * 16 + fr][ks * 32 + fq * 8];
            Yi[0] = __builtin_amdgcn_mfma_f32_16x16x32_bf16(a0, hb, Yi[0], 0, 0, 0);
            Yi[1] = __builtin_amdgcn_mfma_f32_16x16x32_bf16(a1, hb, Yi[1], 0, 0, 0);
        }
        #pragma unroll
        for (int m = 0; m < 2; m++)
            #pragma unroll
            for (int r = 0; r < 4; r++) Yi[m][r] *= sEC[m * 16 + fq * 4 + r];
        // intra: LG @ DX
        {
            short8 a0 = *(const short8*)&LG[fr][fq * 8];
            short8 a1 = *(const short8*)&LG[16 + fr][fq * 8];
            short8 dx = *(const short8*)&DXT[w * 16 + fr][fq * 8];
            Yi[0] = __builtin_amdgcn_mfma_f32_16x16x32_bf16(a0, dx, Yi[0], 0, 0, 0);
            Yi[1] = __builtin_amdgcn_mfma_f32_16x16x32_bf16(a1, dx, Yi[1], 0, 0, 0);
        }
        // h decay + update: h = e^{cumQ} h + DXW^T @ B
        {
            float ecq = sEC[31];
            #pragma unroll
            for (int nf = 0; nf < 8; nf++)
                #pragma unroll
                for (int r = 0; r < 4; r++) hacc[nf][r] *= ecq;
            short8 ax = *(const short8*)&DXWT[w * 16 + fr][fq * 8];
            #pragma unroll
            for (int nf = 0; nf < 8; nf++) {
                short8 bb = *(const short8*)&BtT[nf * 16 + fr][fq * 8];
                hacc[nf] = __builtin_amdgcn_mfma_f32_16x16x32_bf16(ax, bb, hacc[nf], 0, 0, 0);
            }
        }
        // epilogue: + D*x, write Yb
        #pragma unroll
        for (int m = 0; m < 2; m++)
            #pragma unroll
            for (int r = 0; r < 4; r++) {
                int tt = m * 16 + fq * 4 + r;
                float xf = bfb(XT[w * 16 + fr][tt]);
                Yb[tt][w * 16 + fr] = fbf(Yi[m][r] + D_h * xf);
            }
        __syncthreads();
        // ---- Phase E: coalesced Y store ----
        {
            u16x8 yv = *(const u16x8*)&Yb[t][e8 * 8];
            *(u16x8*)&y[(tok0 + t) * 512 + h * 64 + e8 * 8] = yv;
        }
        // next chunk's Phase-A barrier protects Yb (A doesn't touch Yb; D's next
        // write to Yb is behind 3 barriers)
    }
}

// ---------------- gate (y * silu(zg)) + RMSNorm * w -> bf16 ----------------
__global__ __launch_bounds__(256) void gate_k(const unsigned short* __restrict__ y,
                                              const unsigned short* __restrict__ zg,
                                              const float* __restrict__ nw,
                                              unsigned short* __restrict__ yn) {
    int tok = blockIdx.x, tid = threadIdx.x;
    size_t base = (size_t)tok * 512;
    float gv[2];
    float q = 0.f;
    #pragma unroll
    for (int j = 0; j < 2; j++) {
        int c = tid + j * 256;
        float yy = bfb(y[base + c]);
        float zz = bfb(zg[base + c]);
        float s = zz / (1.f + expf(-zz));
        float t = yy * s;
        gv[j] = t;
        q += t * t;
    }
    __shared__ float sm[4];
    #pragma unroll
    for (int o = 32; o; o >>= 1) q += __shfl_down(q, o);
    if ((tid & 63) == 0) sm[tid >> 6] = q;
    __syncthreads();
    float ms = (sm[0] + sm[1] + sm[2] + sm[3]) * (1.f / 512.f);
    float r = rsqrtf(ms + LN_EPS);
    #pragma unroll
    for (int j = 0; j < 2; j++) {
        int c = tid + j * 256;
        yn[base + c] = fbf(gv[j] * r * nw[c]);
    }
}

extern "C" void kernel_launch(void* const* d_in, const int* in_sizes, int n_in,
                              void* d_out, int out_size, void* d_ws, size_t ws_size,
                              hipStream_t stream) {
    if (n_in < 22) return;
    static const int setup_sizes[22] = {8388608,256,256,329728,3072,768,8,8,8,512,
                                        131072,256,65536,256,256,256,256,65536,256,256,65536,256};
    for (int i = 0; i < 22; i++) if (in_sizes[i] != setup_sizes[i]) return;

    const float* z      = (const float*)d_in[0];
    const float* ln1w   = (const float*)d_in[1];
    const float* ln1b   = (const float*)d_in[2];
    const float* inW    = (const float*)d_in[3];
    const float* convw  = (const float*)d_in[4];
    const float* convb  = (const float*)d_in[5];
    const float* dtb    = (const float*)d_in[6];
    const float* Alog   = (const float*)d_in[7];
    const float* Dp     = (const float*)d_in[8];
    const float* normw  = (const float*)d_in[9];
    const float* outW   = (const float*)d_in[10];
    const float* ffg    = (const float*)d_in[11];
    const float* ffv    = (const float*)d_in[12];
    const float* ffb    = (const float*)d_in[13];
    const float* ln2w   = (const float*)d_in[14];
    const float* ln2b   = (const float*)d_in[15];
    const float* fc1g   = (const float*)d_in[16];
    const float* fc1v   = (const float*)d_in[17];
    const float* fc1b   = (const float*)d_in[18];
    const float* fc2g   = (const float*)d_in[19];
    const float* fc2v   = (const float*)d_in[20];
    const float* fc2b   = (const float*)d_in[21];
    float* out = (float*)d_out;
    (void)out_size;

    char* ws = (char*)d_ws;
    const size_t SLOT_A = (size_t)NTOK * 768 * 2;
    const size_t SLOT_B = (size_t)NTOK * 512 * 2;
    const size_t SLOT_C = (size_t)NTOK * 512 * 2;
    const size_t SLOT_D = (size_t)NTOK * 256 * 2;
    const size_t SLOT_E = (size_t)NTOK * 8 * 4;
    const size_t SLOT_W = (size_t)256 * 256 * 2;
    const size_t SLOT_WI = (size_t)1288 * 256 * 2;
    const size_t SLOT_WO = (size_t)256 * 512 * 2;
    char* pA = ws;
    char* pB = pA + SLOT_A;
    char* pC = pB + SLOT_B;
    char* pD = pC + SLOT_C;
    char* pE = pD + SLOT_D;
    char* pW = pE + SLOT_E;
    char* pWI = pW + 3 * SLOT_W;
    char* pWO = pWI + SLOT_WI;
    size_t need = SLOT_A + SLOT_B + SLOT_C + SLOT_D + SLOT_E + 3 * SLOT_W + SLOT_WI + SLOT_WO;
    if (ws_size < need) return;

    unsigned short* xbc = (unsigned short*)pA;
    unsigned short* yn  = (unsigned short*)pA;
    unsigned short* t2  = (unsigned short*)(pA + (size_t)NTOK * 512 * 2);
    unsigned short* y   = (unsigned short*)pB;
    float*          z2  = (float*)pB;
    unsigned short* zgb = (unsigned short*)pC;
    unsigned short* u   = (unsigned short*)pD;
    unsigned short* m1  = (unsigned short*)pD;
    unsigned short* h1  = (unsigned short*)pD;
    float*          dts = (float*)pE;
    unsigned short* wff  = (unsigned short*)pW;
    unsigned short* wfc1 = (unsigned short*)(pW + SLOT_W);
    unsigned short* wfc2 = (unsigned short*)(pW + 2 * SLOT_W);
    unsigned short* inWb = (unsigned short*)pWI;
    unsigned short* outWb = (unsigned short*)pWO;

    cvt_k<<<(1288 * 256 + 255) / 256, 256, 0, stream>>>(inW, inWb, 1288 * 256);
    cvt_k<<<(256 * 512 + 255) / 256, 256, 0, stream>>>(outW, outWb, 256 * 512);
    wnorm_k<<<256, 256, 0, stream>>>(ffg,  ffv,  wff);
    wnorm_k<<<256, 256, 0, stream>>>(fc1g, fc1v, wfc1);
    wnorm_k<<<256, 256, 0, stream>>>(fc2g, fc2v, wfc2);
    ln_k<<<NTOK, 256, 0, stream>>>(z, ln1w, ln1b, u);
    gemm_k<1><<<dim3(256, 10), 256, 0, stream>>>(u, inWb, 256, 1280,
                                                 zgb, nullptr, nullptr, nullptr, xbc);
    dt_k<<<NTOK * 8 / 256, 256, 0, stream>>>(u, inWb, dtb, dts);
    conv_k<<<dim3(12, 64), 256, 0, stream>>>(xbc, convw, convb);
    ssd_k<<<NBATCH * NHEADS, 256, 0, stream>>>(xbc, dts, Alog, Dp, y);
    gate_k<<<NTOK, 256, 0, stream>>>(y, zgb, normw, yn);
    gemm_k<0><<<dim3(256, 2), 256, 0, stream>>>(yn, outWb, 512, 256,
                                                m1, nullptr, nullptr, nullptr, nullptr);
    gemm_k<2><<<dim3(256, 2), 256, 0, stream>>>(m1, wff, 256, 256,
                                                nullptr, z2, ffb, z, nullptr);
    ln_k<<<NTOK, 256, 0, stream>>>(z2, ln2w, ln2b, t2);
    gemm_k<3><<<dim3(256, 2), 256, 0, stream>>>(t2, wfc1, 256, 256,
                                                h1, nullptr, fc1b, nullptr, nullptr);
    gemm_k<2><<<dim3(256, 2), 256, 0, stream>>>(h1, wfc2, 256, 256,
                                                nullptr, out, fc2b, z2, nullptr);
}